// Round 3
// baseline (148.832 us; speedup 1.0000x reference)
//
#include <hip/hip_runtime.h>

typedef _Float16 half8 __attribute__((ext_vector_type(8)));
typedef _Float16 half4_t __attribute__((ext_vector_type(4)));
typedef float float4_t __attribute__((ext_vector_type(4)));

#define SB 32            // samples per tile
#define NT 256           // threads per block (4 waves)
#define TPB 8            // tiles per block (weights amortized across these)
#define RS (SB * 8)      // chunk-row stride in fp16 elems (256)

__device__ __forceinline__ float fast_tanh(float x) {
  float e = __builtin_amdgcn_exp2f(x * 2.8853900817779268f);   // e^(2x)
  return fmaf(-2.f, __builtin_amdgcn_rcpf(1.f + e), 1.f);
}
__device__ __forceinline__ float sigmoid4(float z) {
  float e = __builtin_amdgcn_exp2f(-z * 1.4426950408889634f);  // e^(-z)
  return 4.f * __builtin_amdgcn_rcpf(1.f + e);
}
__device__ __forceinline__ half8 pack8(float4_t lo, float4_t hi) {
  half8 r;
#pragma unroll
  for (int j = 0; j < 4; ++j) { r[j] = (_Float16)lo[j]; r[j + 4] = (_Float16)hi[j]; }
  return r;
}

// 128xSB GEMM layer from register-resident A-frags; out = tanh(W@actT + b)
// written chunk-major (next layer's B operand). Wave wv owns m-tiles mt0,mt1.
template <int KS>
__device__ __forceinline__ void gemm_r(const half8* __restrict__ a0,
                                       const half8* __restrict__ a1,
                                       const _Float16* __restrict__ inB,
                                       const float* __restrict__ biasL,
                                       _Float16* __restrict__ outB,
                                       int quad, int l16, int mt0, int mt1) {
  float4_t acc0[2], acc1[2];
#pragma unroll
  for (int nt = 0; nt < 2; ++nt) {
    acc0[nt] = (float4_t){0.f, 0.f, 0.f, 0.f};
    acc1[nt] = (float4_t){0.f, 0.f, 0.f, 0.f};
  }
#pragma unroll
  for (int kk = 0; kk < KS; ++kk) {
#pragma unroll
    for (int nt = 0; nt < 2; ++nt) {
      half8 b = *(const half8*)(inB + (kk * 4 + quad) * RS + (nt * 16 + l16) * 8);
      acc0[nt] = __builtin_amdgcn_mfma_f32_16x16x32_f16(a0[kk], b, acc0[nt], 0, 0, 0);
      acc1[nt] = __builtin_amdgcn_mfma_f32_16x16x32_f16(a1[kk], b, acc1[nt], 0, 0, 0);
    }
  }
  const float4_t bv0 = *(const float4_t*)(biasL + mt0 * 16 + quad * 4);
  const float4_t bv1 = *(const float4_t*)(biasL + mt1 * 16 + quad * 4);
  const int ob0 = mt0 * 16 + quad * 4;
  const int ob1 = mt1 * 16 + quad * 4;
#pragma unroll
  for (int nt = 0; nt < 2; ++nt) {
    const int s = nt * 16 + l16;
    half4_t h0, h1;
#pragma unroll
    for (int r = 0; r < 4; ++r) {
      h0[r] = (_Float16)fast_tanh(acc0[nt][r] + bv0[r]);
      h1[r] = (_Float16)fast_tanh(acc1[nt][r] + bv1[r]);
    }
    *(half4_t*)(outB + (ob0 >> 3) * RS + s * 8 + (ob0 & 7)) = h0;
    *(half4_t*)(outB + (ob1 >> 3) * RS + s * 8 + (ob1 & 7)) = h1;
  }
}

__global__ __launch_bounds__(NT, 2) void bnet_main(
    const float* __restrict__ x, const float* __restrict__ meang,
    const float* __restrict__ stdg, const float* __restrict__ w1,
    const float* __restrict__ b1, const float* __restrict__ w21,
    const float* __restrict__ b21, const float* __restrict__ w22,
    const float* __restrict__ b22, const float* __restrict__ wm1,
    const float* __restrict__ bm1, const float* __restrict__ wm2,
    const float* __restrict__ bm2, const float* __restrict__ w31,
    const float* __restrict__ b31, const float* __restrict__ w32,
    const float* __restrict__ b32, float* __restrict__ out, int ntiles) {
  __shared__ __align__(16) _Float16 xb[SB * 32];
  __shared__ __align__(16) _Float16 bufH[SB * 128];
  __shared__ __align__(16) _Float16 bufA[SB * 128];
  __shared__ __align__(16) _Float16 bufB[SB * 128];
  __shared__ __align__(16) _Float16 bufC[SB * 128];
  __shared__ __align__(16) float bias_l[5 * 128];
  __shared__ __align__(16) _Float16 w4l[5 * 128];
  __shared__ float b345[5];
  __shared__ __align__(16) float part[NT * 5];

  const int tid = threadIdx.x;
  const int wv = tid >> 6;
  const int lane = tid & 63;
  const int quad = lane >> 4;
  const int l16 = lane & 15;
  const int mt0 = wv * 2, mt1 = mt0 + 1;

  // ---- one-time staging (biases, W4, b31/b32) ----
  for (int i = tid; i < 640; i += NT) {
    int layer = i >> 7, idx = i & 127;
    const float* src = (layer == 0) ? b1 : (layer == 1) ? b21
                     : (layer == 2) ? b22 : (layer == 3) ? bm1 : bm2;
    bias_l[i] = src[idx];
    int r = i >> 7, k = i & 127;
    w4l[i] = (_Float16)((r < 3) ? w31[r * 128 + k] : w32[(r - 3) * 128 + k]);
  }
  if (tid < 5) b345[tid] = (tid < 3) ? b31[tid] : b32[tid - 3];
  // zero xb chunks 1..3 (constant across tiles; only chunk 0 is re-staged)
  if (tid < 96) {
    half8 z;
#pragma unroll
    for (int j = 0; j < 8; ++j) z[j] = (_Float16)0.f;
    *(half8*)(xb + ((tid >> 5) + 1) * RS + (tid & 31) * 8) = z;
  }

  // ---- register-resident weight fragments (loaded once per block) ----
  half8 A1[2];
  half8 A21[2][4], A22[2][4], AM1[2][4], AM2[2][4];
#pragma unroll
  for (int m = 0; m < 2; ++m) {
    const int row = (mt0 + m) * 16 + l16;
    half8 v;
#pragma unroll
    for (int j = 0; j < 8; ++j) v[j] = (_Float16)0.f;
    if (quad == 0) {
#pragma unroll
      for (int j = 0; j < 6; ++j) v[j] = (_Float16)w1[row * 6 + j];
    }
    A1[m] = v;
#pragma unroll
    for (int kk = 0; kk < 4; ++kk) {
      const int base = row * 128 + kk * 32 + quad * 8;
      A21[m][kk] = pack8(*(const float4_t*)(w21 + base), *(const float4_t*)(w21 + base + 4));
      A22[m][kk] = pack8(*(const float4_t*)(w22 + base), *(const float4_t*)(w22 + base + 4));
      AM1[m][kk] = pack8(*(const float4_t*)(wm1 + base), *(const float4_t*)(wm1 + base + 4));
      AM2[m][kk] = pack8(*(const float4_t*)(wm2 + base), *(const float4_t*)(wm2 + base + 4));
    }
  }

  // ---- prefetch x for first tile ----
  const int tile0 = blockIdx.x * TPB;
  float xr[6];
  if (tid < SB) {
    const int tc = (tile0 < ntiles) ? tile0 : (ntiles - 1);
    const float* xp = x + ((size_t)tc * SB + tid) * 6;
#pragma unroll
    for (int j = 0; j < 6; ++j) xr[j] = xp[j];
  }

  for (int t = 0; t < TPB; ++t) {
    const int tile = tile0 + t;
    if (tile >= ntiles) break;   // uniform across block
    float xc[6];
    if (tid < SB) {
      half8 v;
#pragma unroll
      for (int j = 0; j < 6; ++j) { v[j] = (_Float16)xr[j]; xc[j] = xr[j]; }
      v[6] = (_Float16)0.f; v[7] = (_Float16)0.f;
      *(half8*)(xb + tid * 8) = v;
      // prefetch next tile's x (latency hidden behind the 5 layers)
      const int tn = (tile + 1 < ntiles) ? (tile + 1) : (ntiles - 1);
      const float* xp = x + ((size_t)tn * SB + tid) * 6;
#pragma unroll
      for (int j = 0; j < 6; ++j) xr[j] = xp[j];
    }
    __syncthreads();

    gemm_r<1>(&A1[0], &A1[1], xb, bias_l, bufH, quad, l16, mt0, mt1);        // h
    __syncthreads();
    gemm_r<4>(A21[0], A21[1], bufH, bias_l + 128, bufA, quad, l16, mt0, mt1); // x21
    gemm_r<4>(A22[0], A22[1], bufH, bias_l + 256, bufB, quad, l16, mt0, mt1); // x22
    __syncthreads();
    gemm_r<4>(AM1[0], AM1[1], bufA, bias_l + 384, bufH, quad, l16, mt0, mt1); // xm1
    gemm_r<4>(AM2[0], AM2[1], bufB, bias_l + 512, bufC, quad, l16, mt0, mt1); // xm2
    __syncthreads();

    // L4 partials: 5 outputs x SB samples, k split over 8 segments of 16
    {
      const int s = tid & 31, q = tid >> 5;
      half8 x1a = *(const half8*)(bufH + (2 * q + 0) * RS + s * 8);
      half8 x1b = *(const half8*)(bufH + (2 * q + 1) * RS + s * 8);
      half8 x2a = *(const half8*)(bufC + (2 * q + 0) * RS + s * 8);
      half8 x2b = *(const half8*)(bufC + (2 * q + 1) * RS + s * 8);
      float res[5];
#pragma unroll
      for (int j = 0; j < 5; ++j) {
        const _Float16* wr = w4l + j * 128 + q * 16;
        half8 wa = *(const half8*)(wr);
        half8 wb = *(const half8*)(wr + 8);
        half8 xa = (j < 3) ? x1a : x2a;
        half8 xcv = (j < 3) ? x1b : x2b;
        float acc = 0.f;
#pragma unroll
        for (int e = 0; e < 8; ++e) acc = fmaf((float)xa[e], (float)wa[e], acc);
#pragma unroll
        for (int e = 0; e < 8; ++e) acc = fmaf((float)xcv[e], (float)wb[e], acc);
        res[j] = acc;
      }
#pragma unroll
      for (int j = 0; j < 5; ++j) part[tid * 5 + j] = res[j];
    }
    __syncthreads();

    if (tid < SB) {
      const int s = tid;
      float r[5];
#pragma unroll
      for (int j = 0; j < 5; ++j) {
        float a = 0.f;
#pragma unroll
        for (int q = 0; q < 8; ++q) a += part[(q * 32 + s) * 5 + j];
        r[j] = a;
      }
      float u0 = -(r[0] + b345[0]);
      float u1 = -(r[1] + b345[1]);
      float u2 = -(r[2] + b345[2]);
      float p0 = sigmoid4(r[3] + b345[3]);
      float p1 = sigmoid4(r[4] + b345[4]);
      float px = xc[0] * stdg[0] + meang[0];
      float vx = xc[1] * stdg[1] + meang[1];
      float py = xc[2] * stdg[2] + meang[2];
      float vy = xc[3] * stdg[3] + meang[3];
      float pz = xc[4] * stdg[4] + meang[4];
      float vz = xc[5] * stdg[5] + meang[5];
      float dx = px - 10.f, dy = py - 10.f, dz = pz - 9.f;
      float dx2 = dx * dx, dy2 = dy * dy, dz2 = dz * dz;
      float dx3 = dx2 * dx, dy3 = dy2 * dy, dz3 = dz2 * dz;
      float barrier = dx3 * dx + dy3 * dy + dz3 * dz - 2401.f;  // R^4
      float bdot = 4.f * (dx3 * vx + dy3 * vy + dz3 * vz);
      float Lf2b = 12.f * (dx2 * vx * vx + dy2 * vy * vy + dz2 * vz * vz);
      float g0 = -4.f * dx3, g1 = -4.f * dy3, g2 = -4.f * dz3;
      float hv = Lf2b + (p0 + p1) * bdot + p0 * p1 * barrier;
      float Gu = g0 * u0 + g1 * u1 + g2 * u2;
      float GG = g0 * g0 + g1 * g1 + g2 * g2;
      float lam = fmaxf(Gu - hv, 0.f) / GG;
      float* op = out + ((size_t)tile * SB + s) * 3;
      op[0] = u0 - lam * g0;
      op[1] = u1 - lam * g1;
      op[2] = u2 - lam * g2;
    }
    __syncthreads();
  }
}

extern "C" void kernel_launch(void* const* d_in, const int* in_sizes, int n_in,
                              void* d_out, int out_size, void* d_ws, size_t ws_size,
                              hipStream_t stream) {
  const float* x    = (const float*)d_in[0];
  const float* mean = (const float*)d_in[1];
  const float* stdv = (const float*)d_in[2];
  const float* w1   = (const float*)d_in[3];
  const float* b1   = (const float*)d_in[4];
  const float* w21  = (const float*)d_in[5];
  const float* b21  = (const float*)d_in[6];
  const float* w22  = (const float*)d_in[7];
  const float* b22  = (const float*)d_in[8];
  const float* wm1  = (const float*)d_in[9];
  const float* bm1  = (const float*)d_in[10];
  const float* wm2  = (const float*)d_in[11];
  const float* bm2  = (const float*)d_in[12];
  const float* w31  = (const float*)d_in[13];
  const float* b31  = (const float*)d_in[14];
  const float* w32  = (const float*)d_in[15];
  const float* b32  = (const float*)d_in[16];
  float* out = (float*)d_out;
  const int batch = in_sizes[0] / 6;
  const int ntiles = batch / SB;
  const int nblk = (ntiles + TPB - 1) / TPB;

  hipLaunchKernelGGL(bnet_main, dim3(nblk), dim3(NT), 0, stream,
                     x, mean, stdv, w1, b1, w21, b21, w22, b22,
                     wm1, bm1, wm2, bm2, w31, b31, w32, b32, out, ntiles);
}

// Round 4
// 133.372 us; speedup vs baseline: 1.1159x; 1.1159x over previous
//
#include <hip/hip_runtime.h>

typedef _Float16 half8 __attribute__((ext_vector_type(8)));
typedef _Float16 half4_t __attribute__((ext_vector_type(4)));
typedef float float4_t __attribute__((ext_vector_type(4)));
typedef float float2_t __attribute__((ext_vector_type(2)));

#define SB 32            // samples per block
#define NT 256           // threads per block (4 waves)
#define RS (SB * 8)      // chunk-row stride in fp16 elems (256)

// d_ws fp16 element offsets (weights, MFMA-chunk-major)
#define OFF_W1   0       // [128][32] chunk-major, k>=6 zero-padded
#define OFF_W21  4096
#define OFF_W22  20480
#define OFF_WM1  36864
#define OFF_WM2  53248
#define OFF_W4A  69632   // L4 A-frags: 2 chains x KC16, rows>=cnt zeroed (4096 elems)
#define OFF_BIAS 73728   // fp32[640]: b1,b21,b22,bm1,bm2 (cast region)
#define WS_HELEMS 73728

__device__ __forceinline__ float fast_tanh(float x) {
  float e = __builtin_amdgcn_exp2f(x * 2.8853900817779268f);   // e^(2x)
  return fmaf(-2.f, __builtin_amdgcn_rcpf(1.f + e), 1.f);
}
__device__ __forceinline__ float sigmoid4(float z) {
  float e = __builtin_amdgcn_exp2f(-z * 1.4426950408889634f);  // e^(-z)
  return 4.f * __builtin_amdgcn_rcpf(1.f + e);
}

__global__ void prepack(const float* __restrict__ w1, const float* __restrict__ w21,
                        const float* __restrict__ w22, const float* __restrict__ wm1,
                        const float* __restrict__ wm2, const float* __restrict__ w31,
                        const float* __restrict__ w32, const float* __restrict__ b1,
                        const float* __restrict__ b21, const float* __restrict__ b22,
                        const float* __restrict__ bm1, const float* __restrict__ bm2,
                        _Float16* __restrict__ ws) {
  const int stride = gridDim.x * blockDim.x;
  for (int i = blockIdx.x * blockDim.x + threadIdx.x; i < WS_HELEMS; i += stride) {
    float v;
    if (i < OFF_W21) {                       // W1: [128][32] chunk-major, KC=4
      int t = i;
      int j = t & 7, c = t >> 3, l16 = c & 15, t1 = c >> 4;
      int k8 = t1 & 3, mt = t1 >> 2;
      int row = mt * 16 + l16, k = k8 * 8 + j;
      v = (k < 6) ? w1[row * 6 + k] : 0.f;
    } else if (i < OFF_W4A) {                // four 128x128 chunk-major, KC=16
      int t = i - OFF_W21;
      int m = t >> 14; t &= 16383;
      const float* src = (m == 0) ? w21 : (m == 1) ? w22 : (m == 2) ? wm1 : wm2;
      int j = t & 7, c = t >> 3, l16 = c & 15, t1 = c >> 4;
      int k8 = t1 & 15, mt = t1 >> 4;
      v = src[(mt * 16 + l16) * 128 + k8 * 8 + j];
    } else {                                 // L4 A-frags, 2 chains
      int t = i - OFF_W4A;
      int j = t & 7, r = t >> 3, l16 = r & 15, q = r >> 4;
      int cc = q & 15, chain = q >> 4;
      int k = cc * 8 + j, m = l16;
      if (chain == 0) v = (m < 3) ? w31[m * 128 + k] : 0.f;
      else            v = (m < 2) ? w32[m * 128 + k] : 0.f;
    }
    ws[i] = (_Float16)v;
  }
  float* bws = (float*)(ws + OFF_BIAS);
  for (int i = blockIdx.x * blockDim.x + threadIdx.x; i < 640; i += stride) {
    int layer = i >> 7, idx = i & 127;
    const float* src = (layer == 0) ? b1 : (layer == 1) ? b21
                     : (layer == 2) ? b22 : (layer == 3) ? bm1 : bm2;
    bws[i] = src[idx];
  }
}

// 128x32 GEMM layer: out = tanh(W @ actT + b), chunk-major LDS in/out.
__device__ __forceinline__ void gemm128(const _Float16* __restrict__ Wg,
                                        const float* __restrict__ biasG,
                                        const _Float16* __restrict__ inB,
                                        _Float16* __restrict__ outB,
                                        int quad, int l16, int mt0, int mt1) {
  const float4_t bv0 = *(const float4_t*)(biasG + mt0 * 16 + quad * 4);
  const float4_t bv1 = *(const float4_t*)(biasG + mt1 * 16 + quad * 4);
  half8 a0[4], a1[4];
#pragma unroll
  for (int kk = 0; kk < 4; ++kk) {
    a0[kk] = *(const half8*)(Wg + ((mt0 * 16 + kk * 4 + quad) * 16 + l16) * 8);
    a1[kk] = *(const half8*)(Wg + ((mt1 * 16 + kk * 4 + quad) * 16 + l16) * 8);
  }
  float4_t acc0[2], acc1[2];
#pragma unroll
  for (int nt = 0; nt < 2; ++nt) {
    acc0[nt] = (float4_t){0.f, 0.f, 0.f, 0.f};
    acc1[nt] = (float4_t){0.f, 0.f, 0.f, 0.f};
  }
#pragma unroll
  for (int kk = 0; kk < 4; ++kk) {
#pragma unroll
    for (int nt = 0; nt < 2; ++nt) {
      half8 b = *(const half8*)(inB + (kk * 4 + quad) * RS + (nt * 16 + l16) * 8);
      acc0[nt] = __builtin_amdgcn_mfma_f32_16x16x32_f16(a0[kk], b, acc0[nt], 0, 0, 0);
      acc1[nt] = __builtin_amdgcn_mfma_f32_16x16x32_f16(a1[kk], b, acc1[nt], 0, 0, 0);
    }
  }
  const int ob0 = mt0 * 16 + quad * 4;
  const int ob1 = mt1 * 16 + quad * 4;
#pragma unroll
  for (int nt = 0; nt < 2; ++nt) {
    const int s = nt * 16 + l16;
    half4_t h0, h1;
#pragma unroll
    for (int r = 0; r < 4; ++r) {
      h0[r] = (_Float16)fast_tanh(acc0[nt][r] + bv0[r]);
      h1[r] = (_Float16)fast_tanh(acc1[nt][r] + bv1[r]);
    }
    *(half4_t*)(outB + (ob0 >> 3) * RS + s * 8 + (ob0 & 7)) = h0;
    *(half4_t*)(outB + (ob1 >> 3) * RS + s * 8 + (ob1 & 7)) = h1;
  }
}

__global__ __launch_bounds__(NT, 6) void bnet_main(
    const float* __restrict__ x, const float* __restrict__ meang,
    const float* __restrict__ stdg, const float* __restrict__ b31,
    const float* __restrict__ b32, const _Float16* __restrict__ ws,
    float* __restrict__ out) {
  __shared__ __align__(16) _Float16 bufH[SB * 128];
  __shared__ __align__(16) _Float16 bufA[SB * 128];
  __shared__ __align__(16) _Float16 bufB[SB * 128];

  const int tid = threadIdx.x;
  const int wv = tid >> 6;
  const int lane = tid & 63;
  const int quad = lane >> 4;
  const int l16 = lane & 15;
  const int mt0 = wv * 2, mt1 = mt0 + 1;
  const int s0 = blockIdx.x * SB;
  const float* biasF = (const float*)(ws + OFF_BIAS);

  // ---- L1: B-operand built directly from global x (k zero-padded to 32) ----
  {
    half8 bx[2];
#pragma unroll
    for (int nt = 0; nt < 2; ++nt) {
      half8 v;
#pragma unroll
      for (int j = 0; j < 8; ++j) v[j] = (_Float16)0.f;
      if (quad == 0) {
        const float* xp = x + (size_t)(s0 + nt * 16 + l16) * 6;
        float2_t e0 = *(const float2_t*)(xp);
        float2_t e1 = *(const float2_t*)(xp + 2);
        float2_t e2 = *(const float2_t*)(xp + 4);
        v[0] = (_Float16)e0[0]; v[1] = (_Float16)e0[1];
        v[2] = (_Float16)e1[0]; v[3] = (_Float16)e1[1];
        v[4] = (_Float16)e2[0]; v[5] = (_Float16)e2[1];
      }
      bx[nt] = v;
    }
    const float4_t bv0 = *(const float4_t*)(biasF + mt0 * 16 + quad * 4);
    const float4_t bv1 = *(const float4_t*)(biasF + mt1 * 16 + quad * 4);
    half8 a0 = *(const half8*)(ws + OFF_W1 + ((mt0 * 4 + quad) * 16 + l16) * 8);
    half8 a1 = *(const half8*)(ws + OFF_W1 + ((mt1 * 4 + quad) * 16 + l16) * 8);
    float4_t acc0[2], acc1[2];
#pragma unroll
    for (int nt = 0; nt < 2; ++nt) {
      acc0[nt] = (float4_t){0.f, 0.f, 0.f, 0.f};
      acc1[nt] = (float4_t){0.f, 0.f, 0.f, 0.f};
      acc0[nt] = __builtin_amdgcn_mfma_f32_16x16x32_f16(a0, bx[nt], acc0[nt], 0, 0, 0);
      acc1[nt] = __builtin_amdgcn_mfma_f32_16x16x32_f16(a1, bx[nt], acc1[nt], 0, 0, 0);
    }
    const int ob0 = mt0 * 16 + quad * 4;
    const int ob1 = mt1 * 16 + quad * 4;
#pragma unroll
    for (int nt = 0; nt < 2; ++nt) {
      const int s = nt * 16 + l16;
      half4_t h0, h1;
#pragma unroll
      for (int r = 0; r < 4; ++r) {
        h0[r] = (_Float16)fast_tanh(acc0[nt][r] + bv0[r]);
        h1[r] = (_Float16)fast_tanh(acc1[nt][r] + bv1[r]);
      }
      *(half4_t*)(bufH + (ob0 >> 3) * RS + s * 8 + (ob0 & 7)) = h0;
      *(half4_t*)(bufH + (ob1 >> 3) * RS + s * 8 + (ob1 & 7)) = h1;
    }
  }
  __syncthreads();

  gemm128(ws + OFF_W21, biasF + 128, bufH, bufA, quad, l16, mt0, mt1);  // x21
  gemm128(ws + OFF_W22, biasF + 256, bufH, bufB, quad, l16, mt0, mt1);  // x22
  __syncthreads();
  gemm128(ws + OFF_WM1, biasF + 384, bufA, bufH, quad, l16, mt0, mt1);  // xm1
  __syncthreads();
  gemm128(ws + OFF_WM2, biasF + 512, bufB, bufA, quad, l16, mt0, mt1);  // xm2
  __syncthreads();

  // ---- L4 + QP epilogue: wave 0 only, 16 MFMAs, no cross-lane needed ----
  if (wv == 0) {
    half8 a4[2][4];
#pragma unroll
    for (int c = 0; c < 2; ++c)
#pragma unroll
      for (int kk = 0; kk < 4; ++kk)
        a4[c][kk] = *(const half8*)(ws + OFF_W4A +
                                    ((c * 16 + kk * 4 + quad) * 16 + l16) * 8);
    float4_t acc[2][2];
#pragma unroll
    for (int c = 0; c < 2; ++c)
#pragma unroll
      for (int nt = 0; nt < 2; ++nt) acc[c][nt] = (float4_t){0.f, 0.f, 0.f, 0.f};
#pragma unroll
    for (int kk = 0; kk < 4; ++kk)
#pragma unroll
      for (int nt = 0; nt < 2; ++nt) {
        half8 b1f = *(const half8*)(bufH + (kk * 4 + quad) * RS + (nt * 16 + l16) * 8);
        half8 b2f = *(const half8*)(bufA + (kk * 4 + quad) * RS + (nt * 16 + l16) * 8);
        acc[0][nt] = __builtin_amdgcn_mfma_f32_16x16x32_f16(a4[0][kk], b1f, acc[0][nt], 0, 0, 0);
        acc[1][nt] = __builtin_amdgcn_mfma_f32_16x16x32_f16(a4[1][kk], b2f, acc[1][nt], 0, 0, 0);
      }
    if (quad == 0) {   // rows 0..3 of C live in lanes 0-15, regs 0-3
      const float m0 = meang[0], m1 = meang[1], m2 = meang[2];
      const float m3 = meang[3], m4 = meang[4], m5 = meang[5];
      const float sd0 = stdg[0], sd1 = stdg[1], sd2 = stdg[2];
      const float sd3 = stdg[3], sd4 = stdg[4], sd5 = stdg[5];
      const float c31_0 = b31[0], c31_1 = b31[1], c31_2 = b31[2];
      const float c32_0 = b32[0], c32_1 = b32[1];
#pragma unroll
      for (int nt = 0; nt < 2; ++nt) {
        const int s = nt * 16 + l16;
        float u0 = -(acc[0][nt][0] + c31_0);
        float u1 = -(acc[0][nt][1] + c31_1);
        float u2 = -(acc[0][nt][2] + c31_2);
        float p0 = sigmoid4(acc[1][nt][0] + c32_0);
        float p1 = sigmoid4(acc[1][nt][1] + c32_1);
        const float* xp = x + (size_t)(s0 + s) * 6;
        float2_t e0 = *(const float2_t*)(xp);
        float2_t e1 = *(const float2_t*)(xp + 2);
        float2_t e2 = *(const float2_t*)(xp + 4);
        float px = e0[0] * sd0 + m0, vx = e0[1] * sd1 + m1;
        float py = e1[0] * sd2 + m2, vy = e1[1] * sd3 + m3;
        float pz = e2[0] * sd4 + m4, vz = e2[1] * sd5 + m5;
        float dx = px - 10.f, dy = py - 10.f, dz = pz - 9.f;
        float dx2 = dx * dx, dy2 = dy * dy, dz2 = dz * dz;
        float dx3 = dx2 * dx, dy3 = dy2 * dy, dz3 = dz2 * dz;
        float barrier = dx3 * dx + dy3 * dy + dz3 * dz - 2401.f;  // R^4
        float bdot = 4.f * (dx3 * vx + dy3 * vy + dz3 * vz);
        float Lf2b = 12.f * (dx2 * vx * vx + dy2 * vy * vy + dz2 * vz * vz);
        float g0 = -4.f * dx3, g1 = -4.f * dy3, g2 = -4.f * dz3;
        float hv = Lf2b + (p0 + p1) * bdot + p0 * p1 * barrier;
        float Gu = g0 * u0 + g1 * u1 + g2 * u2;
        float GG = g0 * g0 + g1 * g1 + g2 * g2;
        float lam = fmaxf(Gu - hv, 0.f) / GG;
        float* op = out + (size_t)(s0 + s) * 3;
        op[0] = u0 - lam * g0;
        op[1] = u1 - lam * g1;
        op[2] = u2 - lam * g2;
      }
    }
  }
}

extern "C" void kernel_launch(void* const* d_in, const int* in_sizes, int n_in,
                              void* d_out, int out_size, void* d_ws, size_t ws_size,
                              hipStream_t stream) {
  const float* x    = (const float*)d_in[0];
  const float* mean = (const float*)d_in[1];
  const float* stdv = (const float*)d_in[2];
  const float* w1   = (const float*)d_in[3];
  const float* b1   = (const float*)d_in[4];
  const float* w21  = (const float*)d_in[5];
  const float* b21  = (const float*)d_in[6];
  const float* w22  = (const float*)d_in[7];
  const float* b22  = (const float*)d_in[8];
  const float* wm1  = (const float*)d_in[9];
  const float* bm1  = (const float*)d_in[10];
  const float* wm2  = (const float*)d_in[11];
  const float* bm2  = (const float*)d_in[12];
  const float* w31  = (const float*)d_in[13];
  const float* b31  = (const float*)d_in[14];
  const float* w32  = (const float*)d_in[15];
  const float* b32  = (const float*)d_in[16];
  _Float16* ws = (_Float16*)d_ws;
  float* out = (float*)d_out;
  const int batch = in_sizes[0] / 6;

  hipLaunchKernelGGL(prepack, dim3(96), dim3(NT), 0, stream,
                     w1, w21, w22, wm1, wm2, w31, w32,
                     b1, b21, b22, bm1, bm2, ws);
  hipLaunchKernelGGL(bnet_main, dim3(batch / SB), dim3(NT), 0, stream,
                     x, mean, stdv, b31, b32, (const _Float16*)ws, out);
}

// Round 6
// 126.386 us; speedup vs baseline: 1.1776x; 1.0553x over previous
//
#include <hip/hip_runtime.h>

typedef _Float16 half8 __attribute__((ext_vector_type(8)));
typedef _Float16 half4_t __attribute__((ext_vector_type(4)));
typedef __fp16 fp16x2 __attribute__((ext_vector_type(2)));
typedef float float4_t __attribute__((ext_vector_type(4)));
typedef float float2_t __attribute__((ext_vector_type(2)));

#define SB 32            // samples per block
#define NT 512           // threads per block (8 waves, 1 m-tile each)
#define RS (SB * 8)      // chunk-row stride in fp16 elems (256)

// d_ws fp16 element offsets (weights, MFMA-chunk-major, pre-scaled)
#define OFF_W1   0       // [128][32] chunk-major, k>=6 zero-padded, x2log2e
#define OFF_W21  4096
#define OFF_W22  20480
#define OFF_WM1  36864
#define OFF_WM2  53248
#define OFF_W4A  69632   // L4 A-frags: chain0=w31 (raw), chain1=w32 x(-log2e)
#define OFF_BIAS 73728   // fp32[640]: b1..bm2, all x2log2e (acc-init values)
#define WS_HELEMS 73728

#define SCL_TANH 2.8853900817779268f   // 2*log2(e)
#define SCL_SIG  -1.4426950408889634f  // -log2(e)

// input already scaled by 2log2e: tanh = 1 - 2/(1+exp2(a))
__device__ __forceinline__ float tanh_pre(float a) {
  float e = __builtin_amdgcn_exp2f(a);
  return fmaf(-2.f, __builtin_amdgcn_rcpf(1.f + e), 1.f);
}
__device__ __forceinline__ half4_t pack4(float v0, float v1, float v2, float v3) {
  fp16x2 lo = __builtin_amdgcn_cvt_pkrtz(v0, v1);
  fp16x2 hi = __builtin_amdgcn_cvt_pkrtz(v2, v3);
  half4_t h;
  h[0] = (_Float16)lo[0]; h[1] = (_Float16)lo[1];
  h[2] = (_Float16)hi[0]; h[3] = (_Float16)hi[1];
  return h;
}

__global__ void prepack(const float* __restrict__ w1, const float* __restrict__ w21,
                        const float* __restrict__ w22, const float* __restrict__ wm1,
                        const float* __restrict__ wm2, const float* __restrict__ w31,
                        const float* __restrict__ w32, const float* __restrict__ b1,
                        const float* __restrict__ b21, const float* __restrict__ b22,
                        const float* __restrict__ bm1, const float* __restrict__ bm2,
                        _Float16* __restrict__ ws) {
  const int stride = gridDim.x * blockDim.x;
  for (int i = blockIdx.x * blockDim.x + threadIdx.x; i < WS_HELEMS; i += stride) {
    float v;
    if (i < OFF_W21) {                       // W1: [128][32] chunk-major, KC=4
      int t = i;
      int j = t & 7, c = t >> 3, l16 = c & 15, t1 = c >> 4;
      int k8 = t1 & 3, mt = t1 >> 2;
      int row = mt * 16 + l16, k = k8 * 8 + j;
      v = (k < 6) ? w1[row * 6 + k] * SCL_TANH : 0.f;
    } else if (i < OFF_W4A) {                // four 128x128 chunk-major, KC=16
      int t = i - OFF_W21;
      int m = t >> 14; t &= 16383;
      const float* src = (m == 0) ? w21 : (m == 1) ? w22 : (m == 2) ? wm1 : wm2;
      int j = t & 7, c = t >> 3, l16 = c & 15, t1 = c >> 4;
      int k8 = t1 & 15, mt = t1 >> 4;
      v = src[(mt * 16 + l16) * 128 + k8 * 8 + j] * SCL_TANH;
    } else {                                 // L4 A-frags, 2 chains
      int t = i - OFF_W4A;
      int j = t & 7, r = t >> 3, l16 = r & 15, q = r >> 4;
      int cc = q & 15, chain = q >> 4;
      int k = cc * 8 + j, m = l16;
      if (chain == 0) v = (m < 3) ? w31[m * 128 + k] : 0.f;
      else            v = (m < 2) ? w32[m * 128 + k] * SCL_SIG : 0.f;
    }
    ws[i] = (_Float16)v;
  }
  float* bws = (float*)(ws + OFF_BIAS);
  for (int i = blockIdx.x * blockDim.x + threadIdx.x; i < 640; i += stride) {
    int layer = i >> 7, idx = i & 127;
    const float* src = (layer == 0) ? b1 : (layer == 1) ? b21
                     : (layer == 2) ? b22 : (layer == 3) ? bm1 : bm2;
    bws[i] = src[idx] * SCL_TANH;
  }
}

// 16-row x 32-sample layer slice from register A-frags; bias pre-folded into
// acc init; tanh fused; chunk-major LDS out.
__device__ __forceinline__ void layer128(const half8* __restrict__ A, float4_t bv,
                                         const _Float16* __restrict__ inB,
                                         _Float16* __restrict__ outB,
                                         int quad, int l16, int wv) {
  float4_t acc[2];
  acc[0] = bv; acc[1] = bv;
#pragma unroll
  for (int kk = 0; kk < 4; ++kk) {
#pragma unroll
    for (int nt = 0; nt < 2; ++nt) {
      half8 b = *(const half8*)(inB + (kk * 4 + quad) * RS + (nt * 16 + l16) * 8);
      acc[nt] = __builtin_amdgcn_mfma_f32_16x16x32_f16(A[kk], b, acc[nt], 0, 0, 0);
    }
  }
  const int ob = wv * 16 + quad * 4;
  _Float16* base = outB + (ob >> 3) * RS + (ob & 7);
#pragma unroll
  for (int nt = 0; nt < 2; ++nt) {
    const int s = nt * 16 + l16;
    half4_t h = pack4(tanh_pre(acc[nt][0]), tanh_pre(acc[nt][1]),
                      tanh_pre(acc[nt][2]), tanh_pre(acc[nt][3]));
    *(half4_t*)(base + s * 8) = h;
  }
}

__global__ __launch_bounds__(NT, 6) void bnet_main(
    const float* __restrict__ x, const float* __restrict__ meang,
    const float* __restrict__ stdg, const float* __restrict__ b31,
    const float* __restrict__ b32, const _Float16* __restrict__ ws,
    float* __restrict__ out) {
  __shared__ __align__(16) _Float16 bufH[SB * 128];
  __shared__ __align__(16) _Float16 bufA[SB * 128];
  __shared__ __align__(16) _Float16 bufB[SB * 128];
  __shared__ __align__(16) _Float16 bufC[SB * 128];

  const int tid = threadIdx.x;
  const int wv = tid >> 6;          // 0..7 = m-tile
  const int lane = tid & 63;
  const int quad = lane >> 4;
  const int l16 = lane & 15;
  const int s0 = blockIdx.x * SB;
  const float* biasF = (const float*)(ws + OFF_BIAS);
  const int arow = (wv * 16 + quad * 4);   // C rows this lane owns

  // ---- prologue loads: L1 A-frag + bias, prefetch L21 frags ----
  half8 A1 = *(const half8*)(ws + OFF_W1 + ((wv * 4 + quad) * 16 + l16) * 8);
  float4_t bv1 = *(const float4_t*)(biasF + arow);
  float4_t bv21 = *(const float4_t*)(biasF + 128 + arow);
  float4_t bv22 = *(const float4_t*)(biasF + 256 + arow);
  float4_t bvm1 = *(const float4_t*)(biasF + 384 + arow);
  float4_t bvm2 = *(const float4_t*)(biasF + 512 + arow);
  half8 A21[4];
#pragma unroll
  for (int kk = 0; kk < 4; ++kk)
    A21[kk] = *(const half8*)(ws + OFF_W21 + ((wv * 16 + kk * 4 + quad) * 16 + l16) * 8);

  // ---- L1: B built from global x (K=32 zero-padded) ----
  {
    float4_t acc[2];
    acc[0] = bv1; acc[1] = bv1;
#pragma unroll
    for (int nt = 0; nt < 2; ++nt) {
      half8 v;
#pragma unroll
      for (int j = 0; j < 8; ++j) v[j] = (_Float16)0.f;
      if (quad == 0) {
        const float* xp = x + (size_t)(s0 + nt * 16 + l16) * 6;
        float2_t e0 = *(const float2_t*)(xp);
        float2_t e1 = *(const float2_t*)(xp + 2);
        float2_t e2 = *(const float2_t*)(xp + 4);
        v[0] = (_Float16)e0[0]; v[1] = (_Float16)e0[1];
        v[2] = (_Float16)e1[0]; v[3] = (_Float16)e1[1];
        v[4] = (_Float16)e2[0]; v[5] = (_Float16)e2[1];
      }
      acc[nt] = __builtin_amdgcn_mfma_f32_16x16x32_f16(A1, v, acc[nt], 0, 0, 0);
    }
    _Float16* base = bufH + (arow >> 3) * RS + (arow & 7);
#pragma unroll
    for (int nt = 0; nt < 2; ++nt) {
      const int s = nt * 16 + l16;
      half4_t h = pack4(tanh_pre(acc[nt][0]), tanh_pre(acc[nt][1]),
                        tanh_pre(acc[nt][2]), tanh_pre(acc[nt][3]));
      *(half4_t*)(base + s * 8) = h;
    }
  }
  // prefetch L22 frags (overlaps barrier drain + L21 compute)
  half8 A22[4];
#pragma unroll
  for (int kk = 0; kk < 4; ++kk)
    A22[kk] = *(const half8*)(ws + OFF_W22 + ((wv * 16 + kk * 4 + quad) * 16 + l16) * 8);
  __syncthreads();                                   // b1

  layer128(A21, bv21, bufH, bufA, quad, l16, wv);    // x21
  half8 AM1[4];                                      // prefetch LM1
#pragma unroll
  for (int kk = 0; kk < 4; ++kk)
    AM1[kk] = *(const half8*)(ws + OFF_WM1 + ((wv * 16 + kk * 4 + quad) * 16 + l16) * 8);
  layer128(A22, bv22, bufH, bufB, quad, l16, wv);    // x22
  __syncthreads();                                   // b2

  half8 AM2[4];                                      // prefetch LM2
#pragma unroll
  for (int kk = 0; kk < 4; ++kk)
    AM2[kk] = *(const half8*)(ws + OFF_WM2 + ((wv * 16 + kk * 4 + quad) * 16 + l16) * 8);
  layer128(AM1, bvm1, bufA, bufH, quad, l16, wv);    // xm1 -> bufH
  layer128(AM2, bvm2, bufB, bufC, quad, l16, wv);    // xm2 -> bufC
  __syncthreads();                                   // b3

  // ---- L4 + QP epilogue: wave 0 only (A rows >= count are zeroed) ----
  if (wv == 0) {
    half8 A4[2][4];
#pragma unroll
    for (int c = 0; c < 2; ++c)
#pragma unroll
      for (int kk = 0; kk < 4; ++kk)
        A4[c][kk] = *(const half8*)(ws + OFF_W4A +
                                    ((c * 16 + kk * 4 + quad) * 16 + l16) * 8);
    float4_t a0[2], a1[2];
#pragma unroll
    for (int nt = 0; nt < 2; ++nt) {
      a0[nt] = (float4_t){0.f, 0.f, 0.f, 0.f};
      a1[nt] = (float4_t){0.f, 0.f, 0.f, 0.f};
      if (quad == 0) {
        a0[nt][0] = b31[0]; a0[nt][1] = b31[1]; a0[nt][2] = b31[2];
        a1[nt][0] = b32[0] * SCL_SIG; a1[nt][1] = b32[1] * SCL_SIG;
      }
    }
#pragma unroll
    for (int kk = 0; kk < 4; ++kk)
#pragma unroll
      for (int nt = 0; nt < 2; ++nt) {
        half8 bh = *(const half8*)(bufH + (kk * 4 + quad) * RS + (nt * 16 + l16) * 8);
        half8 bc = *(const half8*)(bufC + (kk * 4 + quad) * RS + (nt * 16 + l16) * 8);
        a0[nt] = __builtin_amdgcn_mfma_f32_16x16x32_f16(A4[0][kk], bh, a0[nt], 0, 0, 0);
        a1[nt] = __builtin_amdgcn_mfma_f32_16x16x32_f16(A4[1][kk], bc, a1[nt], 0, 0, 0);
      }
    if (quad == 0) {   // rows 0..3 live in lanes 0-15, regs 0-3
      const float m0 = meang[0], m1 = meang[1], m2 = meang[2];
      const float m3 = meang[3], m4 = meang[4], m5 = meang[5];
      const float sd0 = stdg[0], sd1 = stdg[1], sd2 = stdg[2];
      const float sd3 = stdg[3], sd4 = stdg[4], sd5 = stdg[5];
#pragma unroll
      for (int nt = 0; nt < 2; ++nt) {
        const int s = nt * 16 + l16;
        float u0 = -a0[nt][0];
        float u1 = -a0[nt][1];
        float u2 = -a0[nt][2];
        // sigmoid: a1 already = -z*log2e (weights+bias pre-scaled)
        float p0 = 4.f * __builtin_amdgcn_rcpf(1.f + __builtin_amdgcn_exp2f(a1[nt][0]));
        float p1 = 4.f * __builtin_amdgcn_rcpf(1.f + __builtin_amdgcn_exp2f(a1[nt][1]));
        const float* xp = x + (size_t)(s0 + s) * 6;
        float2_t e0 = *(const float2_t*)(xp);
        float2_t e1 = *(const float2_t*)(xp + 2);
        float2_t e2 = *(const float2_t*)(xp + 4);
        float px = e0[0] * sd0 + m0, vx = e0[1] * sd1 + m1;
        float py = e1[0] * sd2 + m2, vy = e1[1] * sd3 + m3;
        float pz = e2[0] * sd4 + m4, vz = e2[1] * sd5 + m5;
        float dx = px - 10.f, dy = py - 10.f, dz = pz - 9.f;
        float dx2 = dx * dx, dy2 = dy * dy, dz2 = dz * dz;
        float dx3 = dx2 * dx, dy3 = dy2 * dy, dz3 = dz2 * dz;
        float barrier = dx3 * dx + dy3 * dy + dz3 * dz - 2401.f;  // R^4
        float bdot = 4.f * (dx3 * vx + dy3 * vy + dz3 * vz);
        float Lf2b = 12.f * (dx2 * vx * vx + dy2 * vy * vy + dz2 * vz * vz);
        float g0 = -4.f * dx3, g1 = -4.f * dy3, g2 = -4.f * dz3;
        float hv = Lf2b + (p0 + p1) * bdot + p0 * p1 * barrier;
        float Gu = g0 * u0 + g1 * u1 + g2 * u2;
        float GG = g0 * g0 + g1 * g1 + g2 * g2;
        float lam = fmaxf(Gu - hv, 0.f) / GG;
        float* op = out + (size_t)(s0 + s) * 3;
        op[0] = u0 - lam * g0;
        op[1] = u1 - lam * g1;
        op[2] = u2 - lam * g2;
      }
    }
  }
}

extern "C" void kernel_launch(void* const* d_in, const int* in_sizes, int n_in,
                              void* d_out, int out_size, void* d_ws, size_t ws_size,
                              hipStream_t stream) {
  const float* x    = (const float*)d_in[0];
  const float* mean = (const float*)d_in[1];
  const float* stdv = (const float*)d_in[2];
  const float* w1   = (const float*)d_in[3];
  const float* b1   = (const float*)d_in[4];
  const float* w21  = (const float*)d_in[5];
  const float* b21  = (const float*)d_in[6];
  const float* w22  = (const float*)d_in[7];
  const float* b22  = (const float*)d_in[8];
  const float* wm1  = (const float*)d_in[9];
  const float* bm1  = (const float*)d_in[10];
  const float* wm2  = (const float*)d_in[11];
  const float* bm2  = (const float*)d_in[12];
  const float* w31  = (const float*)d_in[13];
  const float* b31  = (const float*)d_in[14];
  const float* w32  = (const float*)d_in[15];
  const float* b32  = (const float*)d_in[16];
  _Float16* ws = (_Float16*)d_ws;
  float* out = (float*)d_out;
  const int batch = in_sizes[0] / 6;

  hipLaunchKernelGGL(prepack, dim3(96), dim3(256), 0, stream,
                     w1, w21, w22, wm1, wm2, w31, w32,
                     b1, b21, b22, bm1, bm2, ws);
  hipLaunchKernelGGL(bnet_main, dim3(batch / SB), dim3(NT), 0, stream,
                     x, mean, stdv, b31, b32, (const _Float16*)ws, out);
}

// Round 7
// 120.773 us; speedup vs baseline: 1.2323x; 1.0465x over previous
//
#include <hip/hip_runtime.h>

typedef _Float16 half8 __attribute__((ext_vector_type(8)));
typedef _Float16 half4_t __attribute__((ext_vector_type(4)));
typedef __fp16 fp16x2 __attribute__((ext_vector_type(2)));
typedef float float4_t __attribute__((ext_vector_type(4)));
typedef float float2_t __attribute__((ext_vector_type(2)));

#define SB 64            // samples per block
#define NT 512           // threads per block (8 waves, 1 m-tile each, 4 n-tiles)
#define RS (SB * 8)      // chunk-row stride in fp16 elems (512)

// d_ws fp16 element offsets (weights, MFMA-chunk-major, pre-scaled)
#define OFF_W1   0       // [128][32] chunk-major, k>=6 zero-padded, x2log2e
#define OFF_W21  4096
#define OFF_W22  20480
#define OFF_WM1  36864
#define OFF_WM2  53248
#define OFF_W4A  69632   // L4 A-frags: chain0=w31 (raw), chain1=w32 x(-log2e)
#define OFF_BIAS 73728   // fp32[640]: b1..bm2, all x2log2e (acc-init values)
#define WS_HELEMS 73728

#define SCL_TANH 2.8853900817779268f   // 2*log2(e)
#define SCL_SIG  -1.4426950408889634f  // -log2(e)

// input already scaled by 2log2e: tanh = 1 - 2/(1+exp2(a))
__device__ __forceinline__ float tanh_pre(float a) {
  float e = __builtin_amdgcn_exp2f(a);
  return fmaf(-2.f, __builtin_amdgcn_rcpf(1.f + e), 1.f);
}
__device__ __forceinline__ half4_t pack4(float v0, float v1, float v2, float v3) {
  fp16x2 lo = __builtin_amdgcn_cvt_pkrtz(v0, v1);
  fp16x2 hi = __builtin_amdgcn_cvt_pkrtz(v2, v3);
  half4_t h;
  h[0] = (_Float16)lo[0]; h[1] = (_Float16)lo[1];
  h[2] = (_Float16)hi[0]; h[3] = (_Float16)hi[1];
  return h;
}

__global__ void prepack(const float* __restrict__ w1, const float* __restrict__ w21,
                        const float* __restrict__ w22, const float* __restrict__ wm1,
                        const float* __restrict__ wm2, const float* __restrict__ w31,
                        const float* __restrict__ w32, const float* __restrict__ b1,
                        const float* __restrict__ b21, const float* __restrict__ b22,
                        const float* __restrict__ bm1, const float* __restrict__ bm2,
                        _Float16* __restrict__ ws) {
  const int stride = gridDim.x * blockDim.x;
  for (int i = blockIdx.x * blockDim.x + threadIdx.x; i < WS_HELEMS; i += stride) {
    float v;
    if (i < OFF_W21) {                       // W1: [128][32] chunk-major, KC=4
      int t = i;
      int j = t & 7, c = t >> 3, l16 = c & 15, t1 = c >> 4;
      int k8 = t1 & 3, mt = t1 >> 2;
      int row = mt * 16 + l16, k = k8 * 8 + j;
      v = (k < 6) ? w1[row * 6 + k] * SCL_TANH : 0.f;
    } else if (i < OFF_W4A) {                // four 128x128 chunk-major, KC=16
      int t = i - OFF_W21;
      int m = t >> 14; t &= 16383;
      const float* src = (m == 0) ? w21 : (m == 1) ? w22 : (m == 2) ? wm1 : wm2;
      int j = t & 7, c = t >> 3, l16 = c & 15, t1 = c >> 4;
      int k8 = t1 & 15, mt = t1 >> 4;
      v = src[(mt * 16 + l16) * 128 + k8 * 8 + j] * SCL_TANH;
    } else {                                 // L4 A-frags, 2 chains
      int t = i - OFF_W4A;
      int j = t & 7, r = t >> 3, l16 = r & 15, q = r >> 4;
      int cc = q & 15, chain = q >> 4;
      int k = cc * 8 + j, m = l16;
      if (chain == 0) v = (m < 3) ? w31[m * 128 + k] : 0.f;
      else            v = (m < 2) ? w32[m * 128 + k] * SCL_SIG : 0.f;
    }
    ws[i] = (_Float16)v;
  }
  float* bws = (float*)(ws + OFF_BIAS);
  for (int i = blockIdx.x * blockDim.x + threadIdx.x; i < 640; i += stride) {
    int layer = i >> 7, idx = i & 127;
    const float* src = (layer == 0) ? b1 : (layer == 1) ? b21
                     : (layer == 2) ? b22 : (layer == 3) ? bm1 : bm2;
    bws[i] = src[idx] * SCL_TANH;
  }
}

// 16-row x 64-sample layer slice from register A-frags; bias folded into acc
// init; tanh fused; chunk-major LDS in/out. 4 independent acc chains (ILP).
__device__ __forceinline__ void layer128(const half8* __restrict__ A, float4_t bv,
                                         const _Float16* __restrict__ inB,
                                         _Float16* __restrict__ outB,
                                         int quad, int l16, int wv) {
  float4_t acc[4];
  acc[0] = bv; acc[1] = bv; acc[2] = bv; acc[3] = bv;
#pragma unroll
  for (int kk = 0; kk < 4; ++kk) {
#pragma unroll
    for (int nt = 0; nt < 4; ++nt) {
      half8 b = *(const half8*)(inB + (kk * 4 + quad) * RS + (nt * 16 + l16) * 8);
      acc[nt] = __builtin_amdgcn_mfma_f32_16x16x32_f16(A[kk], b, acc[nt], 0, 0, 0);
    }
  }
  const int ob = wv * 16 + quad * 4;
  _Float16* base = outB + (ob >> 3) * RS + (ob & 7);
#pragma unroll
  for (int nt = 0; nt < 4; ++nt) {
    const int s = nt * 16 + l16;
    half4_t h = pack4(tanh_pre(acc[nt][0]), tanh_pre(acc[nt][1]),
                      tanh_pre(acc[nt][2]), tanh_pre(acc[nt][3]));
    *(half4_t*)(base + s * 8) = h;
  }
}

__global__ __launch_bounds__(NT, 4) void bnet_main(
    const float* __restrict__ x, const float* __restrict__ meang,
    const float* __restrict__ stdg, const float* __restrict__ b31,
    const float* __restrict__ b32, const _Float16* __restrict__ ws,
    float* __restrict__ out) {
  __shared__ __align__(16) _Float16 bufH[SB * 128];
  __shared__ __align__(16) _Float16 bufA[SB * 128];
  __shared__ __align__(16) _Float16 bufB[SB * 128];
  __shared__ __align__(16) _Float16 bufC[SB * 128];

  const int tid = threadIdx.x;
  const int wv = tid >> 6;          // 0..7 = m-tile
  const int lane = tid & 63;
  const int quad = lane >> 4;
  const int l16 = lane & 15;
  const int s0 = blockIdx.x * SB;
  const float* biasF = (const float*)(ws + OFF_BIAS);
  const int arow = (wv * 16 + quad * 4);   // C rows this lane owns

  // ---- prologue: L1 A-frag + biases, prefetch L21 frags ----
  half8 A1 = *(const half8*)(ws + OFF_W1 + ((wv * 4 + quad) * 16 + l16) * 8);
  float4_t bv1 = *(const float4_t*)(biasF + arow);
  float4_t bv21 = *(const float4_t*)(biasF + 128 + arow);
  float4_t bv22 = *(const float4_t*)(biasF + 256 + arow);
  float4_t bvm1 = *(const float4_t*)(biasF + 384 + arow);
  float4_t bvm2 = *(const float4_t*)(biasF + 512 + arow);
  half8 A21[4];
#pragma unroll
  for (int kk = 0; kk < 4; ++kk)
    A21[kk] = *(const half8*)(ws + OFF_W21 + ((wv * 16 + kk * 4 + quad) * 16 + l16) * 8);

  // ---- L1: B built from global x (K=32 zero-padded), 4 n-tiles ----
  {
    float4_t acc[4];
    acc[0] = bv1; acc[1] = bv1; acc[2] = bv1; acc[3] = bv1;
#pragma unroll
    for (int nt = 0; nt < 4; ++nt) {
      half8 v;
#pragma unroll
      for (int j = 0; j < 8; ++j) v[j] = (_Float16)0.f;
      if (quad == 0) {
        const float* xp = x + (size_t)(s0 + nt * 16 + l16) * 6;
        float2_t e0 = *(const float2_t*)(xp);
        float2_t e1 = *(const float2_t*)(xp + 2);
        float2_t e2 = *(const float2_t*)(xp + 4);
        v[0] = (_Float16)e0[0]; v[1] = (_Float16)e0[1];
        v[2] = (_Float16)e1[0]; v[3] = (_Float16)e1[1];
        v[4] = (_Float16)e2[0]; v[5] = (_Float16)e2[1];
      }
      acc[nt] = __builtin_amdgcn_mfma_f32_16x16x32_f16(A1, v, acc[nt], 0, 0, 0);
    }
    _Float16* base = bufH + (arow >> 3) * RS + (arow & 7);
#pragma unroll
    for (int nt = 0; nt < 4; ++nt) {
      const int s = nt * 16 + l16;
      half4_t h = pack4(tanh_pre(acc[nt][0]), tanh_pre(acc[nt][1]),
                        tanh_pre(acc[nt][2]), tanh_pre(acc[nt][3]));
      *(half4_t*)(base + s * 8) = h;
    }
  }
  half8 A22[4];   // prefetch L22 (overlaps barrier drain)
#pragma unroll
  for (int kk = 0; kk < 4; ++kk)
    A22[kk] = *(const half8*)(ws + OFF_W22 + ((wv * 16 + kk * 4 + quad) * 16 + l16) * 8);
  __syncthreads();                                   // b1

  layer128(A21, bv21, bufH, bufA, quad, l16, wv);    // x21: H -> A
  half8 AM1[4];                                      // prefetch LM1
#pragma unroll
  for (int kk = 0; kk < 4; ++kk)
    AM1[kk] = *(const half8*)(ws + OFF_WM1 + ((wv * 16 + kk * 4 + quad) * 16 + l16) * 8);
  layer128(A22, bv22, bufH, bufB, quad, l16, wv);    // x22: H -> B
  half8 AM2[4];                                      // prefetch LM2
#pragma unroll
  for (int kk = 0; kk < 4; ++kk)
    AM2[kk] = *(const half8*)(ws + OFF_WM2 + ((wv * 16 + kk * 4 + quad) * 16 + l16) * 8);
  __syncthreads();                                   // b2

  layer128(AM1, bvm1, bufA, bufC, quad, l16, wv);    // xm1: A -> C
  half8 A4[2][4];                                    // prefetch L4 (waves 0-3)
  if (wv < 4) {
#pragma unroll
    for (int c = 0; c < 2; ++c)
#pragma unroll
      for (int kk = 0; kk < 4; ++kk)
        A4[c][kk] = *(const half8*)(ws + OFF_W4A +
                                    ((c * 16 + kk * 4 + quad) * 16 + l16) * 8);
  }
  layer128(AM2, bvm2, bufB, bufH, quad, l16, wv);    // xm2: B -> H (H free)
  __syncthreads();                                   // b3

  // ---- L4 + QP epilogue: waves 0-3, one 16-sample n-tile each, both chains ----
  if (wv < 4) {
    const int nt = wv;
    float4_t c0 = (float4_t){0.f, 0.f, 0.f, 0.f};
    float4_t c1 = (float4_t){0.f, 0.f, 0.f, 0.f};
    if (quad == 0) {
      c0[0] = b31[0]; c0[1] = b31[1]; c0[2] = b31[2];
      c1[0] = b32[0] * SCL_SIG; c1[1] = b32[1] * SCL_SIG;
    }
#pragma unroll
    for (int kk = 0; kk < 4; ++kk) {
      half8 bh = *(const half8*)(bufC + (kk * 4 + quad) * RS + (nt * 16 + l16) * 8);
      half8 bc = *(const half8*)(bufH + (kk * 4 + quad) * RS + (nt * 16 + l16) * 8);
      c0 = __builtin_amdgcn_mfma_f32_16x16x32_f16(A4[0][kk], bh, c0, 0, 0, 0);
      c1 = __builtin_amdgcn_mfma_f32_16x16x32_f16(A4[1][kk], bc, c1, 0, 0, 0);
    }
    if (quad == 0) {   // rows 0..3 live in lanes 0-15, regs 0-3
      const int s = nt * 16 + l16;
      float u0 = -c0[0];
      float u1 = -c0[1];
      float u2 = -c0[2];
      float p0 = 4.f * __builtin_amdgcn_rcpf(1.f + __builtin_amdgcn_exp2f(c1[0]));
      float p1 = 4.f * __builtin_amdgcn_rcpf(1.f + __builtin_amdgcn_exp2f(c1[1]));
      const float m0 = meang[0], m1 = meang[1], m2 = meang[2];
      const float m3 = meang[3], m4 = meang[4], m5 = meang[5];
      const float sd0 = stdg[0], sd1 = stdg[1], sd2 = stdg[2];
      const float sd3 = stdg[3], sd4 = stdg[4], sd5 = stdg[5];
      const float* xp = x + (size_t)(s0 + s) * 6;
      float2_t e0 = *(const float2_t*)(xp);
      float2_t e1 = *(const float2_t*)(xp + 2);
      float2_t e2 = *(const float2_t*)(xp + 4);
      float px = e0[0] * sd0 + m0, vx = e0[1] * sd1 + m1;
      float py = e1[0] * sd2 + m2, vy = e1[1] * sd3 + m3;
      float pz = e2[0] * sd4 + m4, vz = e2[1] * sd5 + m5;
      float dx = px - 10.f, dy = py - 10.f, dz = pz - 9.f;
      float dx2 = dx * dx, dy2 = dy * dy, dz2 = dz * dz;
      float dx3 = dx2 * dx, dy3 = dy2 * dy, dz3 = dz2 * dz;
      float barrier = dx3 * dx + dy3 * dy + dz3 * dz - 2401.f;  // R^4
      float bdot = 4.f * (dx3 * vx + dy3 * vy + dz3 * vz);
      float Lf2b = 12.f * (dx2 * vx * vx + dy2 * vy * vy + dz2 * vz * vz);
      float g0 = -4.f * dx3, g1 = -4.f * dy3, g2 = -4.f * dz3;
      float hv = Lf2b + (p0 + p1) * bdot + p0 * p1 * barrier;
      float Gu = g0 * u0 + g1 * u1 + g2 * u2;
      float GG = g0 * g0 + g1 * g1 + g2 * g2;
      float lam = fmaxf(Gu - hv, 0.f) / GG;
      float* op = out + (size_t)(s0 + s) * 3;
      op[0] = u0 - lam * g0;
      op[1] = u1 - lam * g1;
      op[2] = u2 - lam * g2;
    }
  }
}

extern "C" void kernel_launch(void* const* d_in, const int* in_sizes, int n_in,
                              void* d_out, int out_size, void* d_ws, size_t ws_size,
                              hipStream_t stream) {
  const float* x    = (const float*)d_in[0];
  const float* mean = (const float*)d_in[1];
  const float* stdv = (const float*)d_in[2];
  const float* w1   = (const float*)d_in[3];
  const float* b1   = (const float*)d_in[4];
  const float* w21  = (const float*)d_in[5];
  const float* b21  = (const float*)d_in[6];
  const float* w22  = (const float*)d_in[7];
  const float* b22  = (const float*)d_in[8];
  const float* wm1  = (const float*)d_in[9];
  const float* bm1  = (const float*)d_in[10];
  const float* wm2  = (const float*)d_in[11];
  const float* bm2  = (const float*)d_in[12];
  const float* w31  = (const float*)d_in[13];
  const float* b31  = (const float*)d_in[14];
  const float* w32  = (const float*)d_in[15];
  const float* b32  = (const float*)d_in[16];
  _Float16* ws = (_Float16*)d_ws;
  float* out = (float*)d_out;
  const int batch = in_sizes[0] / 6;

  hipLaunchKernelGGL(prepack, dim3(96), dim3(256), 0, stream,
                     w1, w21, w22, wm1, wm2, w31, w32,
                     b1, b21, b22, bm1, bm2, ws);
  hipLaunchKernelGGL(bnet_main, dim3(batch / SB), dim3(NT), 0, stream,
                     x, mean, stdv, b31, b32, (const _Float16*)ws, out);
}